// Round 1
// baseline (15888.985 us; speedup 1.0000x reference)
//
#include <hip/hip_runtime.h>
#include <hip/hip_bf16.h>

// RNNLayer: B=64, T=512, D_IN=D_H=D_OUT=1024.
// h' = [x,h]@W_h^T + b_h ; o = [x,h]@W_o^T + b_o
// Split: parallel input-projection GEMM + 512 sequential small recurrent GEMMs.

typedef _Float16 f16;
typedef _Float16 f16x8 __attribute__((ext_vector_type(8)));
typedef _Float16 f16x4 __attribute__((ext_vector_type(4)));
typedef float f32x4 __attribute__((ext_vector_type(4)));

#define T_LEN 512
#define BATCH 64
#define DD 1024
#define M_TOT (BATCH * T_LEN)   // 32768

// ---------- prep: stacked fp16 weights ----------
// Wx[n][k] = W(n)[k]       (input half,   k in [0,1024))
// Wr[n][k] = W(n)[1024+k]  (recurrent half)
// rows n<1024 -> W_h row n ; n>=1024 -> W_o row n-1024
__global__ void k_prep_w(const float* __restrict__ Wh, const float* __restrict__ Wo,
                         f16* __restrict__ Wx, f16* __restrict__ Wr) {
    int n = blockIdx.x;              // 0..2047
    int t4 = threadIdx.x * 4;        // 0..1020
    const float* src = (n < 1024) ? (Wh + (size_t)n * 2048)
                                  : (Wo + (size_t)(n - 1024) * 2048);
    float4 a = *reinterpret_cast<const float4*>(src + t4);
    float4 b = *reinterpret_cast<const float4*>(src + 1024 + t4);
    f16x4 va, vb;
    va[0]=(f16)a.x; va[1]=(f16)a.y; va[2]=(f16)a.z; va[3]=(f16)a.w;
    vb[0]=(f16)b.x; vb[1]=(f16)b.y; vb[2]=(f16)b.z; vb[3]=(f16)b.w;
    *reinterpret_cast<f16x4*>(Wx + (size_t)n*1024 + t4) = va;
    *reinterpret_cast<f16x4*>(Wr + (size_t)n*1024 + t4) = vb;
}

// ---------- initial hidden (f32 -> f16) ----------
__global__ void k_init_h(const float* __restrict__ H0, f16* __restrict__ h) {
    int i = blockIdx.x * 256 + threadIdx.x;   // 65536 total
    h[i] = (f16)H0[i];
}

// ---------- phase 1: input projection GEMM ----------
// A = X f32 [32768][1024] (converted to f16 while staging)
// Bm = Wx f16 [2048][1024]
// n<1024: Xh[m][n] = dot + b_h[n]  (f16, ws)
// n>=1024: Out[m][n-1024] = dot + b_o  (f32, d_out)
__global__ __launch_bounds__(256) void k_gemm1(
    const float* __restrict__ Af, const f16* __restrict__ Bm,
    const float* __restrict__ bh, const float* __restrict__ bo,
    f16* __restrict__ Xh, float* __restrict__ Out)
{
    __shared__ f16 As[128][40];   // +8 pad: 80B row stride, <=2-way conflicts
    __shared__ f16 Bs[128][40];
    int m0 = blockIdx.x * 128;
    int n0 = blockIdx.y * 128;
    int t = threadIdx.x;
    int l = t & 63, wid = t >> 6;
    int wm = wid >> 1, wn = wid & 1;
    int lm = l & 15, lh = l >> 4;

    f32x4 acc[4][4];
    #pragma unroll
    for (int i = 0; i < 4; i++)
        #pragma unroll
        for (int j = 0; j < 4; j++) acc[i][j] = (f32x4){0.f,0.f,0.f,0.f};

    for (int kt = 0; kt < 32; ++kt) {
        int k0 = kt * 32;
        __syncthreads();   // previous iter's frag reads done before overwrite
        // stage A tile 128x32 f32 -> f16 : 1024 quads of 4
        #pragma unroll
        for (int c = t; c < 1024; c += 256) {
            int row = c >> 3, q = c & 7;
            float4 a = *reinterpret_cast<const float4*>(Af + (size_t)(m0+row)*1024 + k0 + q*4);
            f16x4 v; v[0]=(f16)a.x; v[1]=(f16)a.y; v[2]=(f16)a.z; v[3]=(f16)a.w;
            *reinterpret_cast<f16x4*>(&As[row][q*4]) = v;
        }
        // stage B tile 128x32 f16 : 512 chunks of 16B
        #pragma unroll
        for (int c = t; c < 512; c += 256) {
            int row = c >> 2, q = c & 3;
            *reinterpret_cast<float4*>(&Bs[row][q*8]) =
                *reinterpret_cast<const float4*>(Bm + (size_t)(n0+row)*1024 + k0 + q*8);
        }
        __syncthreads();

        f16x8 af[4], bf[4];
        #pragma unroll
        for (int i = 0; i < 4; i++)
            af[i] = *reinterpret_cast<const f16x8*>(&As[64*wm + 16*i + lm][8*lh]);
        #pragma unroll
        for (int j = 0; j < 4; j++)
            bf[j] = *reinterpret_cast<const f16x8*>(&Bs[64*wn + 16*j + lm][8*lh]);
        #pragma unroll
        for (int i = 0; i < 4; i++)
            #pragma unroll
            for (int j = 0; j < 4; j++)
                acc[i][j] = __builtin_amdgcn_mfma_f32_16x16x32_f16(af[i], bf[j], acc[i][j], 0, 0, 0);
    }

    // epilogue: C/D layout col=lane&15, row=(lane>>4)*4+reg
    int r0 = lh * 4;
    bool isH = (n0 < 1024);
    #pragma unroll
    for (int i = 0; i < 4; i++)
        #pragma unroll
        for (int j = 0; j < 4; j++) {
            int gmb = m0 + 64*wm + 16*i + r0;
            int gn  = n0 + 64*wn + 16*j + lm;
            #pragma unroll
            for (int r = 0; r < 4; r++) {
                float v = acc[i][j][r];
                int gm = gmb + r;
                if (isH) Xh[(size_t)gm*1024 + gn] = (f16)(v + bh[gn]);
                else     Out[(size_t)gm*1024 + (gn - 1024)] = v + bo[gn - 1024];
            }
        }
}

// ---------- phase 2: one recurrent step ----------
// fused [64 x 2048] = h_in[64x1024] @ Wr^T
// blocks 0..31: h_out = result + Xh[.,t,.] ; blocks 32..63: Out[.,t,.] += result
__global__ __launch_bounds__(64) void k_step(
    const f16* __restrict__ h_in, const f16* __restrict__ Wr,
    const f16* __restrict__ Xh, f16* __restrict__ h_out,
    float* __restrict__ Out, int t)
{
    int n0 = blockIdx.x * 32;        // fused col base, 0..2016
    int l = threadIdx.x;
    int lm = l & 15, lh = l >> 4;

    f32x4 acc[4][2];
    #pragma unroll
    for (int i = 0; i < 4; i++)
        #pragma unroll
        for (int j = 0; j < 2; j++) acc[i][j] = (f32x4){0.f,0.f,0.f,0.f};

    #pragma unroll 4
    for (int kt = 0; kt < 32; ++kt) {
        int k0 = kt * 32 + lh * 8;
        f16x8 af[4], bf[2];
        #pragma unroll
        for (int i = 0; i < 4; i++)
            af[i] = *reinterpret_cast<const f16x8*>(h_in + (size_t)(16*i + lm)*1024 + k0);
        #pragma unroll
        for (int j = 0; j < 2; j++)
            bf[j] = *reinterpret_cast<const f16x8*>(Wr + (size_t)(n0 + 16*j + lm)*1024 + k0);
        #pragma unroll
        for (int i = 0; i < 4; i++)
            #pragma unroll
            for (int j = 0; j < 2; j++)
                acc[i][j] = __builtin_amdgcn_mfma_f32_16x16x32_f16(af[i], bf[j], acc[i][j], 0, 0, 0);
    }

    int r0 = lh * 4;
    if (n0 < 1024) {
        #pragma unroll
        for (int i = 0; i < 4; i++)
            #pragma unroll
            for (int j = 0; j < 2; j++) {
                int c = n0 + 16*j + lm;
                #pragma unroll
                for (int r = 0; r < 4; r++) {
                    int m = 16*i + r0 + r;   // batch index
                    float v = acc[i][j][r] + (float)Xh[((size_t)m*512 + t)*1024 + c];
                    h_out[(size_t)m*1024 + c] = (f16)v;
                }
            }
    } else {
        #pragma unroll
        for (int i = 0; i < 4; i++)
            #pragma unroll
            for (int j = 0; j < 2; j++) {
                int c = n0 - 1024 + 16*j + lm;
                #pragma unroll
                for (int r = 0; r < 4; r++) {
                    int m = 16*i + r0 + r;
                    size_t o = ((size_t)m*512 + t)*1024 + c;
                    Out[o] += acc[i][j][r];
                }
            }
    }
}

// ---------- workspace layout (bytes) ----------
// [0, 4M)        Wx f16 [2048][1024]
// [4M, 8M)       Wr f16 [2048][1024]
// [8M, 72M)      Xh f16 [32768][1024]
// [72M, ..)      h ping-pong: 2 x 64*1024 f16 (128 KB each)
// total ~72.3 MB

extern "C" void kernel_launch(void* const* d_in, const int* in_sizes, int n_in,
                              void* d_out, int out_size, void* d_ws, size_t ws_size,
                              hipStream_t stream) {
    const float* X  = (const float*)d_in[0];
    const float* H0 = (const float*)d_in[1];
    const float* Wh = (const float*)d_in[2];
    const float* bh = (const float*)d_in[3];
    const float* Wo = (const float*)d_in[4];
    const float* bo = (const float*)d_in[5];
    float* Out = (float*)d_out;

    char* ws = (char*)d_ws;
    f16* Wx = (f16*)(ws);
    f16* Wr = (f16*)(ws + (size_t)4*1024*1024);
    f16* Xh = (f16*)(ws + (size_t)8*1024*1024);
    f16* h0 = (f16*)(ws + (size_t)8*1024*1024 + (size_t)M_TOT*1024*2);
    f16* h1 = h0 + (size_t)BATCH*1024;

    hipLaunchKernelGGL(k_prep_w, dim3(2048), dim3(256), 0, stream, Wh, Wo, Wx, Wr);
    hipLaunchKernelGGL(k_init_h, dim3(256), dim3(256), 0, stream, H0, h0);
    hipLaunchKernelGGL(k_gemm1, dim3(256, 16), dim3(256), 0, stream, X, Wx, bh, bo, Xh, Out);

    f16* hb[2] = {h0, h1};
    for (int t = 0; t < T_LEN; ++t) {
        hipLaunchKernelGGL(k_step, dim3(64), dim3(64), 0, stream,
                           hb[t & 1], Wr, Xh, hb[(t + 1) & 1], Out, t);
    }
}